// Round 8
// baseline (853.837 us; speedup 1.0000x reference)
//
#include <hip/hip_runtime.h>

#define NN 100000
#define NE 1600000
#define NG 128
#define BN_EPS 1e-5f
#define NBKT 64
#define AGG_BLOCKS 2048
#define AGG_WAVES (AGG_BLOCKS * 4)
#define NBUCK 98          // ceil(NN / 1024)
#define BIN_BLOCKS 256
#define BIN_CHUNK 6250    // NE / BIN_BLOCKS exact

typedef short s16x8 __attribute__((ext_vector_type(8)));
typedef float f32x4 __attribute__((ext_vector_type(4)));

static __device__ __forceinline__ unsigned short f2bf(float f) {
    unsigned u = __float_as_uint(f);
    u += 0x7fffu + ((u >> 16) & 1u);   // RNE
    return (unsigned short)(u >> 16);
}
static __device__ __forceinline__ unsigned packbf(float a, float b) {
    return (unsigned)f2bf(a) | ((unsigned)f2bf(b) << 16);
}
static __device__ __forceinline__ float bf_lo(unsigned u) { return __uint_as_float(u << 16); }
static __device__ __forceinline__ float bf_hi(unsigned u) { return __uint_as_float(u & 0xffff0000u); }
static __device__ __forceinline__ float bf2f(ushort u) { return __uint_as_float((unsigned)u << 16); }

// ---------------- pass 0: coarse bucket histogram ----------------
__global__ __launch_bounds__(256) void k_bhist(const int* __restrict__ dst, int* __restrict__ gbh) {
    __shared__ int lh[128];
    int t = threadIdx.x;
    if (t < 128) lh[t] = 0;
    __syncthreads();
    for (int e = blockIdx.x * 256 + t; e < NE; e += gridDim.x * 256)
        atomicAdd(&lh[dst[e] >> 10], 1);
    __syncthreads();
    if (t < 128 && lh[t]) atomicAdd(&gbh[t], lh[t]);
}

// ---------------- bucket base scan (1 block) ----------------
__global__ __launch_bounds__(128) void k_bscan(const int* __restrict__ gbh, int* __restrict__ gbase,
                                               int* __restrict__ gcur, int* __restrict__ row_start) {
    __shared__ int s[128];
    int t = threadIdx.x;
    int v = gbh[t];
    s[t] = v;
    __syncthreads();
    for (int o = 1; o < 128; o <<= 1) {
        int a = (t >= o) ? s[t - o] : 0;
        __syncthreads();
        s[t] += a;
        __syncthreads();
    }
    int ex = s[t] - v;
    gbase[t] = ex;
    gcur[t] = ex;
    if (t == 127) { gbase[128] = s[127]; row_start[NN] = NE; }
}

// ---------------- pass 1: bin edges into bucket regions (time-dense writes) ----------------
__global__ __launch_bounds__(256) void k_bin(const int* __restrict__ src, const int* __restrict__ dst,
                                             int* __restrict__ gcur, int* __restrict__ tmp) {
    __shared__ int lh[128], lb[128], lc[128];
    int t = threadIdx.x;
    if (t < 128) lh[t] = 0;
    __syncthreads();
    int e0 = blockIdx.x * BIN_CHUNK, e1 = e0 + BIN_CHUNK;
    for (int e = e0 + t; e < e1; e += 256) atomicAdd(&lh[dst[e] >> 10], 1);
    __syncthreads();
    if (t < 128) {
        int c = lh[t];
        lb[t] = c ? atomicAdd(&gcur[t], c) : 0;
        lc[t] = 0;
    }
    __syncthreads();
    for (int e = e0 + t; e < e1; e += 256) {
        int d = dst[e];
        int b = d >> 10;
        int off = atomicAdd(&lc[b], 1);
        tmp[lb[b] + off] = (src[e] << 10) | (d & 1023);   // src:17b | dst_lo:10b
    }
}

// ---------------- pass 2: per-bucket counting sort -> esrc, row_start, dinv ----------------
__global__ __launch_bounds__(256) void k_csr(const int* __restrict__ tmp, const int* __restrict__ gbase,
                                             int* __restrict__ esrc, int* __restrict__ row_start,
                                             float* __restrict__ dinv) {
    __shared__ int h[1024], hs[1024], part[256];
    int b = blockIdx.x, t = threadIdx.x;
    int base = gbase[b], end = gbase[b + 1];
#pragma unroll
    for (int k = 0; k < 4; ++k) h[t * 4 + k] = 0;
    __syncthreads();
    for (int i = base + t; i < end; i += 256) atomicAdd(&h[tmp[i] & 1023], 1);
    __syncthreads();
    int l0 = h[t * 4], l1 = h[t * 4 + 1], l2 = h[t * 4 + 2], l3 = h[t * 4 + 3];
    int ssum = l0 + l1 + l2 + l3;
    part[t] = ssum;
    __syncthreads();
    for (int o = 1; o < 256; o <<= 1) {
        int a = (t >= o) ? part[t - o] : 0;
        __syncthreads();
        part[t] += a;
        __syncthreads();
    }
    int ex = part[t] - ssum;
    hs[t * 4]     = ex;
    hs[t * 4 + 1] = ex + l0;
    hs[t * 4 + 2] = ex + l0 + l1;
    hs[t * 4 + 3] = ex + l0 + l1 + l2;
    int n0 = b * 1024 + t * 4;
#pragma unroll
    for (int k = 0; k < 4; ++k) {
        int n = n0 + k;
        if (n < NN) {
            row_start[n] = base + hs[t * 4 + k];
            dinv[n] = rsqrtf((float)h[t * 4 + k] + 1.0f);
        }
    }
    __syncthreads();
    for (int i = base + t; i < end; i += 256) {
        int rec = tmp[i];
        int pos = atomicAdd(&hs[rec & 1023], 1);
        esrc[base + pos] = rec >> 10;
    }
}

// ---------------- x -> bf16 cast ----------------
__global__ __launch_bounds__(256) void k_cast(const float* __restrict__ x, uint4* __restrict__ xb) {
    int i = blockIdx.x * 256 + threadIdx.x;
    if (i >= NN * 16) return;
    float4 a = *(const float4*)(x + (size_t)i * 8);
    float4 b = *(const float4*)(x + (size_t)i * 8 + 4);
    uint4 o;
    o.x = packbf(a.x, a.y);
    o.y = packbf(a.z, a.w);
    o.z = packbf(b.x, b.y);
    o.w = packbf(b.z, b.w);
    xb[i] = o;
}

// ---------------- W -> MFMA fragment order (bf16) ----------------
__global__ __launch_bounds__(64) void k_wfrag(const float* __restrict__ W, ushort* __restrict__ Wf) {
    int unit = blockIdx.x;          // 0..31: ks = unit>>3, nb = unit&7
    int lane = threadIdx.x;
    int ks = unit >> 3, nb = unit & 7;
    int n = nb * 16 + (lane & 15);
    int k0 = ks * 32 + (lane >> 4) * 8;
    ushort o[8];
#pragma unroll
    for (int j = 0; j < 8; ++j) o[j] = f2bf(W[(size_t)(k0 + j) * 128 + n]);
    ushort* p = Wf + ((size_t)unit * 64 + lane) * 8;
#pragma unroll
    for (int j = 0; j < 8; ++j) p[j] = o[j];
}

// ---------------- graph boundaries: gb[g] = lower_bound(batch, g) ----------------
__global__ __launch_bounds__(128) void k_gbounds(const int* __restrict__ batch, int* __restrict__ gb) {
    int g = threadIdx.x;   // 0..127
    int lo = 0, hi = NN;
    while (lo < hi) {
        int mid = (lo + hi) >> 1;
        if (batch[mid] < g) lo = mid + 1; else hi = mid;
    }
    gb[g] = lo;
    if (g == 0) gb[128] = NN;
}

// ---------------- merged: BN finalize (block 0) + W-scale for next layer (blocks 1..32) ----------------
__global__ __launch_bounds__(128) void k_finwscale(const float* __restrict__ S, const float* __restrict__ Q,
                                                   const float* __restrict__ gam, const float* __restrict__ bet,
                                                   float* __restrict__ svec, float* __restrict__ tvec,
                                                   const float* __restrict__ Wnext, float* __restrict__ tW,
                                                   const ushort* __restrict__ Wfb, ushort* __restrict__ Wff) {
    int bid = blockIdx.x;
    int t = threadIdx.x;
    if (bid == 0) {
        __shared__ float ts[128];
        float s = 0.f, q = 0.f;
        for (int k = 0; k < NBKT; ++k) {
            s += S[k * 128 + t];
            q += Q[k * 128 + t];
        }
        float mean = s / (float)NN;
        float var = q / (float)NN - mean * mean;
        float rstd = rsqrtf(fmaxf(var, 0.f) + BN_EPS);
        float sc = gam[t] * rstd;
        float sh = bet[t] - mean * sc;
        svec[t] = sc;
        tvec[t] = sh;
        ts[t] = sh;
        __syncthreads();
        if (Wnext) {
            float acc = 0.f;
            for (int k = 0; k < 128; ++k) acc += ts[k] * Wnext[(size_t)k * 128 + t];
            tW[t] = acc;
        }
    } else {
        __shared__ float sv[32];
        int unit = bid - 1;
        int kbase = (unit >> 3) * 32;
        if (t < 32) {
            int c = kbase + t;
            float s = 0.f, q = 0.f;
            for (int k = 0; k < NBKT; ++k) {
                s += S[k * 128 + c];
                q += Q[k * 128 + c];
            }
            float mean = s / (float)NN;
            float var = q / (float)NN - mean * mean;
            sv[t] = gam[c] * rsqrtf(fmaxf(var, 0.f) + BN_EPS);
        }
        __syncthreads();
        if (t < 64) {
            int ko = (t >> 4) * 8;   // offset within the 32-k window
            const ushort* p = Wfb + ((size_t)unit * 64 + t) * 8;
            ushort* o = Wff + ((size_t)unit * 64 + t) * 8;
#pragma unroll
            for (int j = 0; j < 8; ++j) o[j] = f2bf(bf2f(p[j]) * sv[ko + j]);
        }
    }
}

// ---------------- MFMA GEMM + fused prev-layer norm write ----------------
// hm'[N][128] = dinv[row] * (Xb @ Wf + tW); if svec: out[row][lofs+c] = bf2f(Xb)*svec+tvec
__global__ __launch_bounds__(256) void k_gemm(const ushort* __restrict__ Xb, const ushort* __restrict__ Wf,
                                              const float* __restrict__ tW, const float* __restrict__ dinv,
                                              ushort* __restrict__ hm, const float* __restrict__ svec,
                                              const float* __restrict__ tvec, float* __restrict__ outp,
                                              int lofs) {
    int tid = threadIdx.x;
    int wid = tid >> 6, lane = tid & 63;
    int r0 = blockIdx.x * 64 + wid * 16;
    int m = lane & 15, g = lane >> 4;
    int xrow = r0 + m;
    int xr = (xrow < NN) ? xrow : (NN - 1);
    const ushort* Xrow = Xb + (size_t)xr * 128 + g * 8;
    s16x8 af[4];
#pragma unroll
    for (int ks = 0; ks < 4; ++ks) af[ks] = *(const s16x8*)(Xrow + ks * 32);
    f32x4 acc[8];
#pragma unroll
    for (int nb = 0; nb < 8; ++nb) acc[nb] = (f32x4){0.f, 0.f, 0.f, 0.f};
#pragma unroll
    for (int ks = 0; ks < 4; ++ks) {
#pragma unroll
        for (int nb = 0; nb < 8; ++nb) {
            s16x8 wf = *(const s16x8*)(Wf + ((size_t)(ks * 8 + nb) * 64 + lane) * 8);
            acc[nb] = __builtin_amdgcn_mfma_f32_16x16x32_bf16(wf, af[ks], acc[nb], 0, 0, 0);
        }
    }
    if (xrow < NN) {
        float ds = dinv[xr];
        ushort* orow = hm + (size_t)xrow * 128 + g * 4;
        if (tW) {
#pragma unroll
            for (int nb = 0; nb < 8; ++nb) {
                float4 tw = *(const float4*)(tW + nb * 16 + g * 4);
                ushort4 o;
                o.x = f2bf(ds * (acc[nb][0] + tw.x));
                o.y = f2bf(ds * (acc[nb][1] + tw.y));
                o.z = f2bf(ds * (acc[nb][2] + tw.z));
                o.w = f2bf(ds * (acc[nb][3] + tw.w));
                *(ushort4*)(orow + nb * 16) = o;
            }
        } else {
#pragma unroll
            for (int nb = 0; nb < 8; ++nb) {
                ushort4 o;
                o.x = f2bf(ds * acc[nb][0]);
                o.y = f2bf(ds * acc[nb][1]);
                o.z = f2bf(ds * acc[nb][2]);
                o.w = f2bf(ds * acc[nb][3]);
                *(ushort4*)(orow + nb * 16) = o;
            }
        }
        if (svec) {   // fused norm write of PREVIOUS layer (input Xb == act_{l-1})
            float* zrow = outp + (size_t)xrow * 384 + lofs;
#pragma unroll
            for (int ks = 0; ks < 4; ++ks) {
                int c0 = ks * 32 + g * 8;
                float4 s0 = *(const float4*)(svec + c0);
                float4 s1 = *(const float4*)(svec + c0 + 4);
                float4 t0 = *(const float4*)(tvec + c0);
                float4 t1 = *(const float4*)(tvec + c0 + 4);
                float4 z0, z1;
                z0.x = bf2f((ushort)af[ks][0]) * s0.x + t0.x;
                z0.y = bf2f((ushort)af[ks][1]) * s0.y + t0.y;
                z0.z = bf2f((ushort)af[ks][2]) * s0.z + t0.z;
                z0.w = bf2f((ushort)af[ks][3]) * s0.w + t0.w;
                z1.x = bf2f((ushort)af[ks][4]) * s1.x + t1.x;
                z1.y = bf2f((ushort)af[ks][5]) * s1.y + t1.y;
                z1.z = bf2f((ushort)af[ks][6]) * s1.z + t1.z;
                z1.w = bf2f((ushort)af[ks][7]) * s1.w + t1.w;
                *(float4*)(zrow + c0) = z0;
                *(float4*)(zrow + c0 + 4) = z1;
            }
        }
    }
}

// ---------------- aggregate + bias + relu + fused BN stats (node-pair, 32 gathers in flight) ----------------
__global__ __launch_bounds__(256, 8) void k_agg(const uint* __restrict__ hm32, const int* __restrict__ esrc,
                                                const int* __restrict__ rs, const float* __restrict__ dinv,
                                                const float* __restrict__ bias, uint* __restrict__ act,
                                                float* __restrict__ bnsum, float* __restrict__ bnsq) {
    __shared__ float ls[128], lq[128];
    int tid = threadIdx.x;
    if (tid < 128) { ls[tid] = 0.f; lq[tid] = 0.f; }
    __syncthreads();
    int lane = tid & 63;
    int wgid = blockIdx.x * 4 + (tid >> 6);
    float2 b2 = *(const float2*)(bias + lane * 2);
    float s0 = 0.f, s1 = 0.f, q0 = 0.f, q1 = 0.f;

    for (int base = wgid * 2; base < NN; base += AGG_WAVES * 2) {
        int nA = base, nB = base + 1;
        uint selfA = hm32[(size_t)nA * 64 + lane];
        uint selfB = hm32[(size_t)nB * 64 + lane];
        float aA0 = bf_lo(selfA), aA1 = bf_hi(selfA);
        float aB0 = bf_lo(selfB), aB1 = bf_hi(selfB);

        int iA  = __builtin_amdgcn_readfirstlane(rs[nA]);
        int iM  = __builtin_amdgcn_readfirstlane(rs[nA + 1]);
        int iE  = __builtin_amdgcn_readfirstlane(rs[nB + 1]);
        int iA1 = iM, iB = iM, iB1 = iE;

        int idxA = 0, idxB = 0;
        if (iA < iA1) idxA = esrc[iA + min(min(lane, 15), iA1 - iA - 1)];
        if (iB < iB1) idxB = esrc[iB + min(min(lane, 15), iB1 - iB - 1)];

        while (iA < iA1 || iB < iB1) {
            int cntA = iA1 - iA; cntA = cntA > 16 ? 16 : (cntA < 0 ? 0 : cntA);
            int cntB = iB1 - iB; cntB = cntB > 16 ? 16 : (cntB < 0 ? 0 : cntB);
            int curA = idxA, curB = idxB;
            int inA = iA + cntA, inB = iB + cntB;
            if (inA < iA1) idxA = esrc[inA + min(min(lane, 15), iA1 - inA - 1)];
            if (inB < iB1) idxB = esrc[inB + min(min(lane, 15), iB1 - inB - 1)];
            uint gA[16], gB[16];
            if (cntA) {
#pragma unroll
                for (int u = 0; u < 16; ++u) {
                    int sx = __builtin_amdgcn_readlane(curA, u);
                    sx = (u < cntA) ? sx : NN;
                    gA[u] = hm32[(size_t)sx * 64 + lane];
                }
            }
            if (cntB) {
#pragma unroll
                for (int u = 0; u < 16; ++u) {
                    int sx = __builtin_amdgcn_readlane(curB, u);
                    sx = (u < cntB) ? sx : NN;
                    gB[u] = hm32[(size_t)sx * 64 + lane];
                }
            }
            if (cntA) {
#pragma unroll
                for (int u = 0; u < 16; ++u) { aA0 += bf_lo(gA[u]); aA1 += bf_hi(gA[u]); }
            }
            if (cntB) {
#pragma unroll
                for (int u = 0; u < 16; ++u) { aB0 += bf_lo(gB[u]); aB1 += bf_hi(gB[u]); }
            }
            iA = inA; iB = inB;
        }
        float dA = dinv[nA], dB = dinv[nB];
        float zA0 = fmaxf(fmaf(dA, aA0, b2.x), 0.f);
        float zA1 = fmaxf(fmaf(dA, aA1, b2.y), 0.f);
        float zB0 = fmaxf(fmaf(dB, aB0, b2.x), 0.f);
        float zB1 = fmaxf(fmaf(dB, aB1, b2.y), 0.f);
        act[(size_t)nA * 64 + lane] = packbf(zA0, zA1);
        act[(size_t)nB * 64 + lane] = packbf(zB0, zB1);
        s0 += zA0 + zB0; s1 += zA1 + zB1;
        q0 += zA0 * zA0 + zB0 * zB0; q1 += zA1 * zA1 + zB1 * zB1;
    }
    atomicAdd(&ls[lane * 2],     s0);
    atomicAdd(&ls[lane * 2 + 1], s1);
    atomicAdd(&lq[lane * 2],     q0);
    atomicAdd(&lq[lane * 2 + 1], q1);
    __syncthreads();
    if (tid < 128) {
        int bkt = blockIdx.x & (NBKT - 1);
        atomicAdd(&bnsum[bkt * 128 + tid], ls[tid]);
        atomicAdd(&bnsq[bkt * 128 + tid],  lq[tid]);
    }
}

// ---------------- per-graph pool (no atomics): gout = svec*sum(act) + tvec*cnt ----------------
__global__ __launch_bounds__(256) void k_pool(const ushort* __restrict__ act, const float* __restrict__ svec,
                                              const float* __restrict__ tvec, const int* __restrict__ gb,
                                              float* __restrict__ gout, int lofs) {
    __shared__ float ps[256];
    int g = blockIdx.x;
    int t = threadIdx.x;
    int c = t & 127, half = t >> 7;
    int gs = gb[g], ge = gb[g + 1];
    float sum = 0.f;
    for (int n = gs + half; n < ge; n += 2) sum += bf2f(act[(size_t)n * 128 + c]);
    ps[t] = sum;
    __syncthreads();
    if (t < 128) {
        float tot = ps[t] + ps[t + 128];
        float cnt = (float)(ge - gs);
        gout[(size_t)g * 384 + lofs + t] = svec[t] * tot + tvec[t] * cnt;
    }
}

// ---------------- final layer out write ----------------
__global__ __launch_bounds__(128) void k_norm2(const ushort* __restrict__ act, const float* __restrict__ svec,
                                               const float* __restrict__ tvec, float* __restrict__ outp) {
    int c = threadIdx.x;
    int n0 = blockIdx.x * 64;
    if (n0 >= NN) return;
    int n1 = n0 + 64; if (n1 > NN) n1 = NN;
    float scale = svec[c];
    float shift = tvec[c];
    for (int n = n0; n < n1; ++n)
        outp[(size_t)n * 384 + 256 + c] = bf2f(act[(size_t)n * 128 + c]) * scale + shift;
}

extern "C" void kernel_launch(void* const* d_in, const int* in_sizes, int n_in,
                              void* d_out, int out_size, void* d_ws, size_t ws_size,
                              hipStream_t stream) {
    const float* x = (const float*)d_in[0];
    const int* ei = (const int*)d_in[1];
    const int* src = ei;
    const int* dst = ei + NE;
    const int* batch = (const int*)d_in[2];
    const float *W[3], *b[3], *g[3], *beta[3];
    for (int l = 0; l < 3; ++l) {
        W[l]    = (const float*)d_in[3 + 4 * l];
        b[l]    = (const float*)d_in[4 + 4 * l];
        g[l]    = (const float*)d_in[5 + 4 * l];
        beta[l] = (const float*)d_in[6 + 4 * l];
    }
    float* out = (float*)d_out;
    float* gout = out + (size_t)NN * 384;

    char* ws = (char*)d_ws;
    size_t off = 0;
    auto alloc = [&](size_t bytes) -> char* {
        off = (off + 255) & ~(size_t)255;
        char* p = ws + off;
        off += bytes;
        return p;
    };
    ushort* xb       = (ushort*)alloc((size_t)NN * 256);        // bf16 x
    ushort* act      = (ushort*)alloc((size_t)NN * 256);        // bf16 relu output (pre-BN)
    ushort* hm       = (ushort*)alloc((size_t)(NN + 1) * 256);  // bf16 hm' rows + zero row at NN
    int*    esrc     = (int*)alloc((size_t)NE * 4);
    int*    tmp      = (int*)alloc((size_t)NE * 4);
    int*    row_start= (int*)alloc((size_t)(NN + 1) * 4);
    float*  dinv     = (float*)alloc((size_t)NN * 4);
    float*  bnst     = (float*)alloc((size_t)3 * 2 * NBKT * 128 * 4);   // [layer][sum|sq][NBKT][128]
    ushort* Wf       = (ushort*)alloc(3 * 16384 * 2);
    ushort* Wff      = (ushort*)alloc(16384 * 2);
    float*  svt      = (float*)alloc(3 * 2 * 128 * 4);                  // [layer][s|t][128]
    float*  tW       = (float*)alloc(128 * 4);
    int*    misc     = (int*)alloc(1024 * 4);   // gbh[128], gbase[129], gcur[128], gb[129]
    int* gbh   = misc;
    int* gbase = misc + 128;
    int* gcur  = misc + 384;
    int* gb    = misc + 512;
    (void)ws_size;

    hipMemsetAsync(gbh, 0, 128 * 4, stream);
    hipMemsetAsync(hm + (size_t)NN * 128, 0, 256, stream);              // zero row
    hipMemsetAsync(bnst, 0, (size_t)3 * 2 * NBKT * 128 * 4, stream);

    k_bhist<<<512, 256, 0, stream>>>(dst, gbh);
    k_bscan<<<1, 128, 0, stream>>>(gbh, gbase, gcur, row_start);
    k_bin<<<BIN_BLOCKS, 256, 0, stream>>>(src, dst, gcur, tmp);
    k_csr<<<NBUCK, 256, 0, stream>>>(tmp, gbase, esrc, row_start, dinv);
    k_cast<<<(NN * 16 + 255) / 256, 256, 0, stream>>>(x, (uint4*)xb);
    for (int l = 0; l < 3; ++l) k_wfrag<<<32, 64, 0, stream>>>(W[l], Wf + l * 16384);
    k_gbounds<<<1, 128, 0, stream>>>(batch, gb);

    for (int l = 0; l < 3; ++l) {
        float* S = bnst + (size_t)l * 2 * NBKT * 128;
        float* Q = S + NBKT * 128;
        float* sv = svt + l * 256;
        float* tv = sv + 128;
        const ushort* gin = (l == 0) ? xb : act;
        const ushort* wfrag = (l == 0) ? (Wf + 0) : Wff;
        const float* tw_in = (l == 0) ? nullptr : tW;
        const float* psv = (l == 0) ? nullptr : (svt + (l - 1) * 256);
        const float* ptv = (l == 0) ? nullptr : (svt + (l - 1) * 256 + 128);

        k_gemm<<<(NN + 63) / 64, 256, 0, stream>>>(gin, wfrag, tw_in, dinv, hm,
                                                   psv, ptv, out, (l - 1) * 128);
        k_agg<<<AGG_BLOCKS, 256, 0, stream>>>((const uint*)hm, esrc, row_start, dinv, b[l],
                                              (uint*)act, S, Q);
        k_finwscale<<<(l < 2) ? 33 : 1, 128, 0, stream>>>(S, Q, g[l], beta[l], sv, tv,
                                                          (l < 2) ? W[l + 1] : nullptr, tW,
                                                          (l < 2) ? (Wf + (l + 1) * 16384) : nullptr, Wff);
        k_pool<<<NG, 256, 0, stream>>>(act, sv, tv, gb, gout, l * 128);
    }
    k_norm2<<<(NN + 63) / 64, 128, 0, stream>>>(act, svt + 2 * 256, svt + 2 * 256 + 128, out);
}

// Round 9
// 507.547 us; speedup vs baseline: 1.6823x; 1.6823x over previous
//
#include <hip/hip_runtime.h>

#define NN 100000
#define NE 1600000
#define NG 128
#define BN_EPS 1e-5f
#define NBKT 64
#define AGG_BLOCKS 2048
#define AGG_WAVES (AGG_BLOCKS * 4)
#define NBUCK 98          // ceil(NN / 1024)
#define BIN_BLOCKS 256
#define BIN_CHUNK 6250    // NE / BIN_BLOCKS exact

typedef short s16x8 __attribute__((ext_vector_type(8)));
typedef float f32x4 __attribute__((ext_vector_type(4)));

static __device__ __forceinline__ unsigned short f2bf(float f) {
    unsigned u = __float_as_uint(f);
    u += 0x7fffu + ((u >> 16) & 1u);   // RNE
    return (unsigned short)(u >> 16);
}
static __device__ __forceinline__ unsigned packbf(float a, float b) {
    return (unsigned)f2bf(a) | ((unsigned)f2bf(b) << 16);
}
static __device__ __forceinline__ float bf_lo(unsigned u) { return __uint_as_float(u << 16); }
static __device__ __forceinline__ float bf_hi(unsigned u) { return __uint_as_float(u & 0xffff0000u); }
static __device__ __forceinline__ float bf2f(ushort u) { return __uint_as_float((unsigned)u << 16); }

// ---------------- pass 0: coarse bucket histogram ----------------
__global__ __launch_bounds__(256) void k_bhist(const int* __restrict__ dst, int* __restrict__ gbh) {
    __shared__ int lh[128];
    int t = threadIdx.x;
    if (t < 128) lh[t] = 0;
    __syncthreads();
    for (int e = blockIdx.x * 256 + t; e < NE; e += gridDim.x * 256)
        atomicAdd(&lh[dst[e] >> 10], 1);
    __syncthreads();
    if (t < 128 && lh[t]) atomicAdd(&gbh[t], lh[t]);
}

// ---------------- bucket base scan (1 block) ----------------
__global__ __launch_bounds__(128) void k_bscan(const int* __restrict__ gbh, int* __restrict__ gbase,
                                               int* __restrict__ gcur, int* __restrict__ row_start) {
    __shared__ int s[128];
    int t = threadIdx.x;
    int v = gbh[t];
    s[t] = v;
    __syncthreads();
    for (int o = 1; o < 128; o <<= 1) {
        int a = (t >= o) ? s[t - o] : 0;
        __syncthreads();
        s[t] += a;
        __syncthreads();
    }
    int ex = s[t] - v;
    gbase[t] = ex;
    gcur[t] = ex;
    if (t == 127) { gbase[128] = s[127]; row_start[NN] = NE; }
}

// ---------------- pass 1: bin edges into bucket regions (time-dense writes) ----------------
__global__ __launch_bounds__(256) void k_bin(const int* __restrict__ src, const int* __restrict__ dst,
                                             int* __restrict__ gcur, int* __restrict__ tmp) {
    __shared__ int lh[128], lb[128], lc[128];
    int t = threadIdx.x;
    if (t < 128) lh[t] = 0;
    __syncthreads();
    int e0 = blockIdx.x * BIN_CHUNK, e1 = e0 + BIN_CHUNK;
    for (int e = e0 + t; e < e1; e += 256) atomicAdd(&lh[dst[e] >> 10], 1);
    __syncthreads();
    if (t < 128) {
        int c = lh[t];
        lb[t] = c ? atomicAdd(&gcur[t], c) : 0;
        lc[t] = 0;
    }
    __syncthreads();
    for (int e = e0 + t; e < e1; e += 256) {
        int d = dst[e];
        int b = d >> 10;
        int off = atomicAdd(&lc[b], 1);
        tmp[lb[b] + off] = (src[e] << 10) | (d & 1023);   // src:17b | dst_lo:10b
    }
}

// ---------------- pass 2: per-bucket counting sort -> esrc, row_start, dinv ----------------
__global__ __launch_bounds__(256) void k_csr(const int* __restrict__ tmp, const int* __restrict__ gbase,
                                             int* __restrict__ esrc, int* __restrict__ row_start,
                                             float* __restrict__ dinv) {
    __shared__ int h[1024], hs[1024], part[256];
    int b = blockIdx.x, t = threadIdx.x;
    int base = gbase[b], end = gbase[b + 1];
#pragma unroll
    for (int k = 0; k < 4; ++k) h[t * 4 + k] = 0;
    __syncthreads();
    for (int i = base + t; i < end; i += 256) atomicAdd(&h[tmp[i] & 1023], 1);
    __syncthreads();
    int l0 = h[t * 4], l1 = h[t * 4 + 1], l2 = h[t * 4 + 2], l3 = h[t * 4 + 3];
    int ssum = l0 + l1 + l2 + l3;
    part[t] = ssum;
    __syncthreads();
    for (int o = 1; o < 256; o <<= 1) {
        int a = (t >= o) ? part[t - o] : 0;
        __syncthreads();
        part[t] += a;
        __syncthreads();
    }
    int ex = part[t] - ssum;
    hs[t * 4]     = ex;
    hs[t * 4 + 1] = ex + l0;
    hs[t * 4 + 2] = ex + l0 + l1;
    hs[t * 4 + 3] = ex + l0 + l1 + l2;
    int n0 = b * 1024 + t * 4;
#pragma unroll
    for (int k = 0; k < 4; ++k) {
        int n = n0 + k;
        if (n < NN) {
            row_start[n] = base + hs[t * 4 + k];
            dinv[n] = rsqrtf((float)h[t * 4 + k] + 1.0f);
        }
    }
    __syncthreads();
    for (int i = base + t; i < end; i += 256) {
        int rec = tmp[i];
        int pos = atomicAdd(&hs[rec & 1023], 1);
        esrc[base + pos] = rec >> 10;
    }
}

// ---------------- x -> bf16 cast ----------------
__global__ __launch_bounds__(256) void k_cast(const float* __restrict__ x, uint4* __restrict__ xb) {
    int i = blockIdx.x * 256 + threadIdx.x;
    if (i >= NN * 16) return;
    float4 a = *(const float4*)(x + (size_t)i * 8);
    float4 b = *(const float4*)(x + (size_t)i * 8 + 4);
    uint4 o;
    o.x = packbf(a.x, a.y);
    o.y = packbf(a.z, a.w);
    o.z = packbf(b.x, b.y);
    o.w = packbf(b.z, b.w);
    xb[i] = o;
}

// ---------------- W -> MFMA fragment order (bf16) ----------------
__global__ __launch_bounds__(64) void k_wfrag(const float* __restrict__ W, ushort* __restrict__ Wf) {
    int unit = blockIdx.x;          // 0..31: ks = unit>>3, nb = unit&7
    int lane = threadIdx.x;
    int ks = unit >> 3, nb = unit & 7;
    int n = nb * 16 + (lane & 15);
    int k0 = ks * 32 + (lane >> 4) * 8;
    ushort o[8];
#pragma unroll
    for (int j = 0; j < 8; ++j) o[j] = f2bf(W[(size_t)(k0 + j) * 128 + n]);
    ushort* p = Wf + ((size_t)unit * 64 + lane) * 8;
#pragma unroll
    for (int j = 0; j < 8; ++j) p[j] = o[j];
}

// ---------------- merged: BN finalize (block 0) + W-scale for next layer (blocks 1..32) ----------------
__global__ __launch_bounds__(128) void k_finwscale(const float* __restrict__ S, const float* __restrict__ Q,
                                                   const float* __restrict__ gam, const float* __restrict__ bet,
                                                   float* __restrict__ svec, float* __restrict__ tvec,
                                                   const float* __restrict__ Wnext, float* __restrict__ tW,
                                                   const ushort* __restrict__ Wfb, ushort* __restrict__ Wff) {
    int bid = blockIdx.x;
    int t = threadIdx.x;
    if (bid == 0) {
        __shared__ float ts[128];
        float s = 0.f, q = 0.f;
        for (int k = 0; k < NBKT; ++k) {
            s += S[k * 128 + t];
            q += Q[k * 128 + t];
        }
        float mean = s / (float)NN;
        float var = q / (float)NN - mean * mean;
        float rstd = rsqrtf(fmaxf(var, 0.f) + BN_EPS);
        float sc = gam[t] * rstd;
        float sh = bet[t] - mean * sc;
        svec[t] = sc;
        tvec[t] = sh;
        ts[t] = sh;
        __syncthreads();
        if (Wnext) {
            float acc = 0.f;
            for (int k = 0; k < 128; ++k) acc += ts[k] * Wnext[(size_t)k * 128 + t];
            tW[t] = acc;
        }
    } else {
        __shared__ float sv[32];
        int unit = bid - 1;
        int kbase = (unit >> 3) * 32;
        if (t < 32) {
            int c = kbase + t;
            float s = 0.f, q = 0.f;
            for (int k = 0; k < NBKT; ++k) {
                s += S[k * 128 + c];
                q += Q[k * 128 + c];
            }
            float mean = s / (float)NN;
            float var = q / (float)NN - mean * mean;
            sv[t] = gam[c] * rsqrtf(fmaxf(var, 0.f) + BN_EPS);
        }
        __syncthreads();
        if (t < 64) {
            int ko = (t >> 4) * 8;   // offset within the 32-k window
            const ushort* p = Wfb + ((size_t)unit * 64 + t) * 8;
            ushort* o = Wff + ((size_t)unit * 64 + t) * 8;
#pragma unroll
            for (int j = 0; j < 8; ++j) o[j] = f2bf(bf2f(p[j]) * sv[ko + j]);
        }
    }
}

// ---------------- MFMA GEMM + fused prev-layer norm write ----------------
// hm'[N][128] = dinv[row] * (Xb @ Wf + tW); if svec: out[row][lofs+c] = bf2f(Xb)*svec+tvec
__global__ __launch_bounds__(256) void k_gemm(const ushort* __restrict__ Xb, const ushort* __restrict__ Wf,
                                              const float* __restrict__ tW, const float* __restrict__ dinv,
                                              ushort* __restrict__ hm, const float* __restrict__ svec,
                                              const float* __restrict__ tvec, float* __restrict__ outp,
                                              int lofs) {
    int tid = threadIdx.x;
    int wid = tid >> 6, lane = tid & 63;
    int r0 = blockIdx.x * 64 + wid * 16;
    int m = lane & 15, g = lane >> 4;
    int xrow = r0 + m;
    int xr = (xrow < NN) ? xrow : (NN - 1);
    const ushort* Xrow = Xb + (size_t)xr * 128 + g * 8;
    s16x8 af[4];
#pragma unroll
    for (int ks = 0; ks < 4; ++ks) af[ks] = *(const s16x8*)(Xrow + ks * 32);
    f32x4 acc[8];
#pragma unroll
    for (int nb = 0; nb < 8; ++nb) acc[nb] = (f32x4){0.f, 0.f, 0.f, 0.f};
#pragma unroll
    for (int ks = 0; ks < 4; ++ks) {
#pragma unroll
        for (int nb = 0; nb < 8; ++nb) {
            s16x8 wf = *(const s16x8*)(Wf + ((size_t)(ks * 8 + nb) * 64 + lane) * 8);
            acc[nb] = __builtin_amdgcn_mfma_f32_16x16x32_bf16(wf, af[ks], acc[nb], 0, 0, 0);
        }
    }
    if (xrow < NN) {
        float ds = dinv[xr];
        ushort* orow = hm + (size_t)xrow * 128 + g * 4;
        if (tW) {
#pragma unroll
            for (int nb = 0; nb < 8; ++nb) {
                float4 tw = *(const float4*)(tW + nb * 16 + g * 4);
                ushort4 o;
                o.x = f2bf(ds * (acc[nb][0] + tw.x));
                o.y = f2bf(ds * (acc[nb][1] + tw.y));
                o.z = f2bf(ds * (acc[nb][2] + tw.z));
                o.w = f2bf(ds * (acc[nb][3] + tw.w));
                *(ushort4*)(orow + nb * 16) = o;
            }
        } else {
#pragma unroll
            for (int nb = 0; nb < 8; ++nb) {
                ushort4 o;
                o.x = f2bf(ds * acc[nb][0]);
                o.y = f2bf(ds * acc[nb][1]);
                o.z = f2bf(ds * acc[nb][2]);
                o.w = f2bf(ds * acc[nb][3]);
                *(ushort4*)(orow + nb * 16) = o;
            }
        }
        if (svec) {   // fused norm write of PREVIOUS layer (input Xb == act_{l-1})
            float* zrow = outp + (size_t)xrow * 384 + lofs;
#pragma unroll
            for (int ks = 0; ks < 4; ++ks) {
                int c0 = ks * 32 + g * 8;
                float4 s0 = *(const float4*)(svec + c0);
                float4 s1 = *(const float4*)(svec + c0 + 4);
                float4 t0 = *(const float4*)(tvec + c0);
                float4 t1 = *(const float4*)(tvec + c0 + 4);
                float4 z0, z1;
                z0.x = bf2f((ushort)af[ks][0]) * s0.x + t0.x;
                z0.y = bf2f((ushort)af[ks][1]) * s0.y + t0.y;
                z0.z = bf2f((ushort)af[ks][2]) * s0.z + t0.z;
                z0.w = bf2f((ushort)af[ks][3]) * s0.w + t0.w;
                z1.x = bf2f((ushort)af[ks][4]) * s1.x + t1.x;
                z1.y = bf2f((ushort)af[ks][5]) * s1.y + t1.y;
                z1.z = bf2f((ushort)af[ks][6]) * s1.z + t1.z;
                z1.w = bf2f((ushort)af[ks][7]) * s1.w + t1.w;
                *(float4*)(zrow + c0) = z0;
                *(float4*)(zrow + c0 + 4) = z1;
            }
        }
    }
}

// ---------------- aggregate + bias + relu + fused BN stats (round-7 form) ----------------
__global__ __launch_bounds__(256) void k_agg(const uint* __restrict__ hm32, const int* __restrict__ esrc,
                                             const int* __restrict__ rs, const float* __restrict__ dinv,
                                             const float* __restrict__ bias, uint* __restrict__ act,
                                             float* __restrict__ bnsum, float* __restrict__ bnsq) {
    __shared__ float ls[128], lq[128];
    int tid = threadIdx.x;
    if (tid < 128) { ls[tid] = 0.f; lq[tid] = 0.f; }
    __syncthreads();
    int lane = tid & 63;
    int wgid = blockIdx.x * 4 + (tid >> 6);
    float2 b2 = *(const float2*)(bias + lane * 2);
    float s0 = 0.f, s1 = 0.f, q0 = 0.f, q1 = 0.f;

    for (int n = wgid; n < NN; n += AGG_WAVES) {
        uint self = hm32[(size_t)n * 64 + lane];
        float a0 = bf_lo(self);
        float a1 = bf_hi(self);

        int i  = __builtin_amdgcn_readfirstlane(rs[n]);
        int i1 = __builtin_amdgcn_readfirstlane(rs[n + 1]);

        int idxv = 0;
        if (i < i1) idxv = esrc[i + min(min(lane, 15), i1 - i - 1)];

        while (i < i1) {
            int cnt = i1 - i;
            cnt = (cnt > 16) ? 16 : cnt;       // wave-uniform
            int cur = idxv;
            int inext = i + cnt;
            if (inext < i1)                    // prefetch next chunk while gathers fly
                idxv = esrc[inext + min(min(lane, 15), i1 - inext - 1)];
            uint g[16];
#pragma unroll
            for (int u = 0; u < 16; ++u) {
                int sidx = __builtin_amdgcn_readlane(cur, u);
                sidx = (u < cnt) ? sidx : NN;  // scalar select -> zero row for pads
                g[u] = hm32[(size_t)sidx * 64 + lane];
            }
#pragma unroll
            for (int u = 0; u < 16; ++u) {
                a0 += bf_lo(g[u]);
                a1 += bf_hi(g[u]);
            }
            i = inext;
        }
        float di = dinv[n];
        float z0 = fmaxf(fmaf(di, a0, b2.x), 0.f);
        float z1 = fmaxf(fmaf(di, a1, b2.y), 0.f);
        act[(size_t)n * 64 + lane] = packbf(z0, z1);
        s0 += z0; s1 += z1;
        q0 += z0 * z0; q1 += z1 * z1;
    }
    atomicAdd(&ls[lane * 2],     s0);
    atomicAdd(&ls[lane * 2 + 1], s1);
    atomicAdd(&lq[lane * 2],     q0);
    atomicAdd(&lq[lane * 2 + 1], q1);
    __syncthreads();
    if (tid < 128) {
        int bkt = blockIdx.x & (NBKT - 1);
        atomicAdd(&bnsum[bkt * 128 + tid], ls[tid]);
        atomicAdd(&bnsq[bkt * 128 + tid],  lq[tid]);
    }
}

// ---------------- per-graph pool: gout += svec*sum(act) + tvec*cnt  (run-length + atomics) ----------------
// 64 nodes per block; wave w handles nodes n0 + 2i + w. Lane covers 2 channels.
__global__ __launch_bounds__(128) void k_pool(const uint* __restrict__ act32, const float* __restrict__ svec,
                                              const float* __restrict__ tvec, const int* __restrict__ batch,
                                              float* __restrict__ gout, int lofs) {
    int t = threadIdx.x;
    int lane = t & 63;
    int w = t >> 6;
    int n0 = blockIdx.x * 64;
    float sc0 = svec[lane * 2], sc1 = svec[lane * 2 + 1];
    float sh0 = tvec[lane * 2], sh1 = tvec[lane * 2 + 1];
    float s0 = 0.f, s1 = 0.f;
    int cnt = 0, curg = -1;
    for (int k = w; k < 64; k += 2) {
        int n = n0 + k;
        if (n >= NN) break;
        int gn = batch[n];
        if (gn != curg) {
            if (cnt) {
                atomicAdd(&gout[(size_t)curg * 384 + lofs + lane * 2],     sc0 * s0 + sh0 * (float)cnt);
                atomicAdd(&gout[(size_t)curg * 384 + lofs + lane * 2 + 1], sc1 * s1 + sh1 * (float)cnt);
            }
            curg = gn; s0 = 0.f; s1 = 0.f; cnt = 0;
        }
        uint v = act32[(size_t)n * 64 + lane];
        s0 += bf_lo(v);
        s1 += bf_hi(v);
        ++cnt;
    }
    if (cnt) {
        atomicAdd(&gout[(size_t)curg * 384 + lofs + lane * 2],     sc0 * s0 + sh0 * (float)cnt);
        atomicAdd(&gout[(size_t)curg * 384 + lofs + lane * 2 + 1], sc1 * s1 + sh1 * (float)cnt);
    }
}

// ---------------- final layer out write ----------------
__global__ __launch_bounds__(128) void k_norm2(const ushort* __restrict__ act, const float* __restrict__ svec,
                                               const float* __restrict__ tvec, float* __restrict__ outp) {
    int c = threadIdx.x;
    int n0 = blockIdx.x * 64;
    if (n0 >= NN) return;
    int n1 = n0 + 64; if (n1 > NN) n1 = NN;
    float scale = svec[c];
    float shift = tvec[c];
    for (int n = n0; n < n1; ++n)
        outp[(size_t)n * 384 + 256 + c] = bf2f(act[(size_t)n * 128 + c]) * scale + shift;
}

extern "C" void kernel_launch(void* const* d_in, const int* in_sizes, int n_in,
                              void* d_out, int out_size, void* d_ws, size_t ws_size,
                              hipStream_t stream) {
    const float* x = (const float*)d_in[0];
    const int* ei = (const int*)d_in[1];
    const int* src = ei;
    const int* dst = ei + NE;
    const int* batch = (const int*)d_in[2];
    const float *W[3], *b[3], *g[3], *beta[3];
    for (int l = 0; l < 3; ++l) {
        W[l]    = (const float*)d_in[3 + 4 * l];
        b[l]    = (const float*)d_in[4 + 4 * l];
        g[l]    = (const float*)d_in[5 + 4 * l];
        beta[l] = (const float*)d_in[6 + 4 * l];
    }
    float* out = (float*)d_out;
    float* gout = out + (size_t)NN * 384;

    char* ws = (char*)d_ws;
    size_t off = 0;
    auto alloc = [&](size_t bytes) -> char* {
        off = (off + 255) & ~(size_t)255;
        char* p = ws + off;
        off += bytes;
        return p;
    };
    ushort* xb       = (ushort*)alloc((size_t)NN * 256);        // bf16 x
    ushort* act      = (ushort*)alloc((size_t)NN * 256);        // bf16 relu output (pre-BN)
    ushort* hm       = (ushort*)alloc((size_t)(NN + 1) * 256);  // bf16 hm' rows + zero row at NN
    int*    esrc     = (int*)alloc((size_t)NE * 4);
    int*    tmp      = (int*)alloc((size_t)NE * 4);
    int*    row_start= (int*)alloc((size_t)(NN + 1) * 4);
    float*  dinv     = (float*)alloc((size_t)NN * 4);
    float*  bnst     = (float*)alloc((size_t)3 * 2 * NBKT * 128 * 4);   // [layer][sum|sq][NBKT][128]
    ushort* Wf       = (ushort*)alloc(3 * 16384 * 2);
    ushort* Wff      = (ushort*)alloc(16384 * 2);
    float*  svt      = (float*)alloc(3 * 2 * 128 * 4);                  // [layer][s|t][128]
    float*  tW       = (float*)alloc(128 * 4);
    int*    misc     = (int*)alloc(512 * 4);   // gbh[128], gbase[129], gcur[128]
    int* gbh   = misc;
    int* gbase = misc + 128;
    int* gcur  = misc + 384;
    (void)ws_size;

    hipMemsetAsync(gbh, 0, 128 * 4, stream);
    hipMemsetAsync(hm + (size_t)NN * 128, 0, 256, stream);              // zero row
    hipMemsetAsync(bnst, 0, (size_t)3 * 2 * NBKT * 128 * 4, stream);
    hipMemsetAsync(gout, 0, (size_t)NG * 384 * 4, stream);

    k_bhist<<<512, 256, 0, stream>>>(dst, gbh);
    k_bscan<<<1, 128, 0, stream>>>(gbh, gbase, gcur, row_start);
    k_bin<<<BIN_BLOCKS, 256, 0, stream>>>(src, dst, gcur, tmp);
    k_csr<<<NBUCK, 256, 0, stream>>>(tmp, gbase, esrc, row_start, dinv);
    k_cast<<<(NN * 16 + 255) / 256, 256, 0, stream>>>(x, (uint4*)xb);
    for (int l = 0; l < 3; ++l) k_wfrag<<<32, 64, 0, stream>>>(W[l], Wf + l * 16384);

    for (int l = 0; l < 3; ++l) {
        float* S = bnst + (size_t)l * 2 * NBKT * 128;
        float* Q = S + NBKT * 128;
        float* sv = svt + l * 256;
        float* tv = sv + 128;
        const ushort* gin = (l == 0) ? xb : act;
        const ushort* wfrag = (l == 0) ? (Wf + 0) : Wff;
        const float* tw_in = (l == 0) ? nullptr : tW;
        const float* psv = (l == 0) ? nullptr : (svt + (l - 1) * 256);
        const float* ptv = (l == 0) ? nullptr : (svt + (l - 1) * 256 + 128);

        k_gemm<<<(NN + 63) / 64, 256, 0, stream>>>(gin, wfrag, tw_in, dinv, hm,
                                                   psv, ptv, out, (l - 1) * 128);
        k_agg<<<AGG_BLOCKS, 256, 0, stream>>>((const uint*)hm, esrc, row_start, dinv, b[l],
                                              (uint*)act, S, Q);
        k_finwscale<<<(l < 2) ? 33 : 1, 128, 0, stream>>>(S, Q, g[l], beta[l], sv, tv,
                                                          (l < 2) ? W[l + 1] : nullptr, tW,
                                                          (l < 2) ? (Wf + (l + 1) * 16384) : nullptr, Wff);
        k_pool<<<(NN + 63) / 64, 128, 0, stream>>>((const uint*)act, sv, tv, batch, gout, l * 128);
    }
    k_norm2<<<(NN + 63) / 64, 128, 0, stream>>>(act, svt + 2 * 256, svt + 2 * 256 + 128, out);
}

// Round 10
// 460.947 us; speedup vs baseline: 1.8524x; 1.1011x over previous
//
#include <hip/hip_runtime.h>

#define NN 100000
#define NE 1600000
#define NG 128
#define BN_EPS 1e-5f
#define NBKT 64
#define AGG_BLOCKS 2048
#define AGG_WAVES (AGG_BLOCKS * 4)
#define NBUCK 98          // ceil(NN / 1024)
#define BIN_BLOCKS 256
#define BIN_CHUNK 6250    // NE / BIN_BLOCKS exact

typedef short s16x8 __attribute__((ext_vector_type(8)));
typedef float f32x4 __attribute__((ext_vector_type(4)));

static __device__ __forceinline__ unsigned short f2bf(float f) {
    unsigned u = __float_as_uint(f);
    u += 0x7fffu + ((u >> 16) & 1u);   // RNE
    return (unsigned short)(u >> 16);
}
static __device__ __forceinline__ unsigned packbf(float a, float b) {
    return (unsigned)f2bf(a) | ((unsigned)f2bf(b) << 16);
}
static __device__ __forceinline__ float bf_lo(unsigned u) { return __uint_as_float(u << 16); }
static __device__ __forceinline__ float bf_hi(unsigned u) { return __uint_as_float(u & 0xffff0000u); }
static __device__ __forceinline__ float bf2f(ushort u) { return __uint_as_float((unsigned)u << 16); }

// ---------------- pass 0: coarse bucket histogram ----------------
__global__ __launch_bounds__(256) void k_bhist(const int* __restrict__ dst, int* __restrict__ gbh) {
    __shared__ int lh[128];
    int t = threadIdx.x;
    if (t < 128) lh[t] = 0;
    __syncthreads();
    for (int e = blockIdx.x * 256 + t; e < NE; e += gridDim.x * 256)
        atomicAdd(&lh[dst[e] >> 10], 1);
    __syncthreads();
    if (t < 128 && lh[t]) atomicAdd(&gbh[t], lh[t]);
}

// ---------------- bucket base scan (1 block) ----------------
__global__ __launch_bounds__(128) void k_bscan(const int* __restrict__ gbh, int* __restrict__ gbase,
                                               int* __restrict__ gcur, int* __restrict__ row_start) {
    __shared__ int s[128];
    int t = threadIdx.x;
    int v = gbh[t];
    s[t] = v;
    __syncthreads();
    for (int o = 1; o < 128; o <<= 1) {
        int a = (t >= o) ? s[t - o] : 0;
        __syncthreads();
        s[t] += a;
        __syncthreads();
    }
    int ex = s[t] - v;
    gbase[t] = ex;
    gcur[t] = ex;
    if (t == 127) { gbase[128] = s[127]; row_start[NN] = NE; }
}

// ---------------- pass 1: bin edges into bucket regions (time-dense writes) ----------------
__global__ __launch_bounds__(256) void k_bin(const int* __restrict__ src, const int* __restrict__ dst,
                                             int* __restrict__ gcur, int* __restrict__ tmp) {
    __shared__ int lh[128], lb[128], lc[128];
    int t = threadIdx.x;
    if (t < 128) lh[t] = 0;
    __syncthreads();
    int e0 = blockIdx.x * BIN_CHUNK, e1 = e0 + BIN_CHUNK;
    for (int e = e0 + t; e < e1; e += 256) atomicAdd(&lh[dst[e] >> 10], 1);
    __syncthreads();
    if (t < 128) {
        int c = lh[t];
        lb[t] = c ? atomicAdd(&gcur[t], c) : 0;
        lc[t] = 0;
    }
    __syncthreads();
    for (int e = e0 + t; e < e1; e += 256) {
        int d = dst[e];
        int b = d >> 10;
        int off = atomicAdd(&lc[b], 1);
        tmp[lb[b] + off] = (src[e] << 10) | (d & 1023);   // src:17b | dst_lo:10b
    }
}

// ---------------- pass 2: per-bucket counting sort -> esrc, row_start, dinv ----------------
__global__ __launch_bounds__(256) void k_csr(const int* __restrict__ tmp, const int* __restrict__ gbase,
                                             int* __restrict__ esrc, int* __restrict__ row_start,
                                             float* __restrict__ dinv) {
    __shared__ int h[1024], hs[1024], part[256];
    int b = blockIdx.x, t = threadIdx.x;
    int base = gbase[b], end = gbase[b + 1];
#pragma unroll
    for (int k = 0; k < 4; ++k) h[t * 4 + k] = 0;
    __syncthreads();
    for (int i = base + t; i < end; i += 256) atomicAdd(&h[tmp[i] & 1023], 1);
    __syncthreads();
    int l0 = h[t * 4], l1 = h[t * 4 + 1], l2 = h[t * 4 + 2], l3 = h[t * 4 + 3];
    int ssum = l0 + l1 + l2 + l3;
    part[t] = ssum;
    __syncthreads();
    for (int o = 1; o < 256; o <<= 1) {
        int a = (t >= o) ? part[t - o] : 0;
        __syncthreads();
        part[t] += a;
        __syncthreads();
    }
    int ex = part[t] - ssum;
    hs[t * 4]     = ex;
    hs[t * 4 + 1] = ex + l0;
    hs[t * 4 + 2] = ex + l0 + l1;
    hs[t * 4 + 3] = ex + l0 + l1 + l2;
    int n0 = b * 1024 + t * 4;
#pragma unroll
    for (int k = 0; k < 4; ++k) {
        int n = n0 + k;
        if (n < NN) {
            row_start[n] = base + hs[t * 4 + k];
            dinv[n] = rsqrtf((float)h[t * 4 + k] + 1.0f);
        }
    }
    __syncthreads();
    for (int i = base + t; i < end; i += 256) {
        int rec = tmp[i];
        int pos = atomicAdd(&hs[rec & 1023], 1);
        esrc[base + pos] = rec >> 10;
    }
}

// ---------------- W -> MFMA fragment order (bf16), all 3 layers in one launch ----------------
__global__ __launch_bounds__(64) void k_wfrag(const float* __restrict__ W0, const float* __restrict__ W1,
                                              const float* __restrict__ W2, ushort* __restrict__ Wf) {
    int layer = blockIdx.x >> 5;    // 0..2
    int unit = blockIdx.x & 31;     // ks = unit>>3, nb = unit&7
    const float* W = (layer == 0) ? W0 : ((layer == 1) ? W1 : W2);
    int lane = threadIdx.x;
    int ks = unit >> 3, nb = unit & 7;
    int n = nb * 16 + (lane & 15);
    int k0 = ks * 32 + (lane >> 4) * 8;
    ushort o[8];
#pragma unroll
    for (int j = 0; j < 8; ++j) o[j] = f2bf(W[(size_t)(k0 + j) * 128 + n]);
    ushort* p = Wf + (size_t)layer * 16384 + ((size_t)unit * 64 + lane) * 8;
#pragma unroll
    for (int j = 0; j < 8; ++j) p[j] = o[j];
}

// ---------------- merged: BN finalize (block 0) + W-scale for next layer (blocks 1..32) ----------------
__global__ __launch_bounds__(128) void k_finwscale(const float* __restrict__ S, const float* __restrict__ Q,
                                                   const float* __restrict__ gam, const float* __restrict__ bet,
                                                   float* __restrict__ svec, float* __restrict__ tvec,
                                                   const float* __restrict__ Wnext, float* __restrict__ tW,
                                                   const ushort* __restrict__ Wfb, ushort* __restrict__ Wff) {
    int bid = blockIdx.x;
    int t = threadIdx.x;
    if (bid == 0) {
        __shared__ float ts[128];
        float s = 0.f, q = 0.f;
        for (int k = 0; k < NBKT; ++k) {
            s += S[k * 128 + t];
            q += Q[k * 128 + t];
        }
        float mean = s / (float)NN;
        float var = q / (float)NN - mean * mean;
        float rstd = rsqrtf(fmaxf(var, 0.f) + BN_EPS);
        float sc = gam[t] * rstd;
        float sh = bet[t] - mean * sc;
        svec[t] = sc;
        tvec[t] = sh;
        ts[t] = sh;
        __syncthreads();
        if (Wnext) {
            float acc = 0.f;
            for (int k = 0; k < 128; ++k) acc += ts[k] * Wnext[(size_t)k * 128 + t];
            tW[t] = acc;
        }
    } else {
        __shared__ float sv[32];
        int unit = bid - 1;
        int kbase = (unit >> 3) * 32;
        if (t < 32) {
            int c = kbase + t;
            float s = 0.f, q = 0.f;
            for (int k = 0; k < NBKT; ++k) {
                s += S[k * 128 + c];
                q += Q[k * 128 + c];
            }
            float mean = s / (float)NN;
            float var = q / (float)NN - mean * mean;
            sv[t] = gam[c] * rsqrtf(fmaxf(var, 0.f) + BN_EPS);
        }
        __syncthreads();
        if (t < 64) {
            int ko = (t >> 4) * 8;   // offset within the 32-k window
            const ushort* p = Wfb + ((size_t)unit * 64 + t) * 8;
            ushort* o = Wff + ((size_t)unit * 64 + t) * 8;
#pragma unroll
            for (int j = 0; j < 8; ++j) o[j] = f2bf(bf2f(p[j]) * sv[ko + j]);
        }
    }
}

// ---------------- MFMA GEMM (pure): hm'[N][128] = dinv[row] * (X @ Wf + tW) ----------------
// X source: xf32 (layer 0, packs fragments in-register) or Xb bf16 (layers 1,2)
__global__ __launch_bounds__(256) void k_gemm(const ushort* __restrict__ Xb, const float* __restrict__ xf32,
                                              const ushort* __restrict__ Wf, const float* __restrict__ tW,
                                              const float* __restrict__ dinv, ushort* __restrict__ hm) {
    int tid = threadIdx.x;
    int wid = tid >> 6, lane = tid & 63;
    int r0 = blockIdx.x * 64 + wid * 16;
    int m = lane & 15, g = lane >> 4;
    int xrow = r0 + m;
    int xr = (xrow < NN) ? xrow : (NN - 1);
    s16x8 af[4];
    if (xf32) {
        const float* Xr = xf32 + (size_t)xr * 128 + g * 8;
#pragma unroll
        for (int ks = 0; ks < 4; ++ks) {
            float4 a = *(const float4*)(Xr + ks * 32);
            float4 b = *(const float4*)(Xr + ks * 32 + 4);
            s16x8 v;
            v[0] = (short)f2bf(a.x); v[1] = (short)f2bf(a.y);
            v[2] = (short)f2bf(a.z); v[3] = (short)f2bf(a.w);
            v[4] = (short)f2bf(b.x); v[5] = (short)f2bf(b.y);
            v[6] = (short)f2bf(b.z); v[7] = (short)f2bf(b.w);
            af[ks] = v;
        }
    } else {
        const ushort* Xrow = Xb + (size_t)xr * 128 + g * 8;
#pragma unroll
        for (int ks = 0; ks < 4; ++ks) af[ks] = *(const s16x8*)(Xrow + ks * 32);
    }
    f32x4 acc[8];
#pragma unroll
    for (int nb = 0; nb < 8; ++nb) acc[nb] = (f32x4){0.f, 0.f, 0.f, 0.f};
#pragma unroll
    for (int ks = 0; ks < 4; ++ks) {
#pragma unroll
        for (int nb = 0; nb < 8; ++nb) {
            s16x8 wf = *(const s16x8*)(Wf + ((size_t)(ks * 8 + nb) * 64 + lane) * 8);
            acc[nb] = __builtin_amdgcn_mfma_f32_16x16x32_bf16(wf, af[ks], acc[nb], 0, 0, 0);
        }
    }
    if (xrow < NN) {
        float ds = dinv[xr];
        ushort* orow = hm + (size_t)xrow * 128 + g * 4;
        if (tW) {
#pragma unroll
            for (int nb = 0; nb < 8; ++nb) {
                float4 tw = *(const float4*)(tW + nb * 16 + g * 4);
                ushort4 o;
                o.x = f2bf(ds * (acc[nb][0] + tw.x));
                o.y = f2bf(ds * (acc[nb][1] + tw.y));
                o.z = f2bf(ds * (acc[nb][2] + tw.z));
                o.w = f2bf(ds * (acc[nb][3] + tw.w));
                *(ushort4*)(orow + nb * 16) = o;
            }
        } else {
#pragma unroll
            for (int nb = 0; nb < 8; ++nb) {
                ushort4 o;
                o.x = f2bf(ds * acc[nb][0]);
                o.y = f2bf(ds * acc[nb][1]);
                o.z = f2bf(ds * acc[nb][2]);
                o.w = f2bf(ds * acc[nb][3]);
                *(ushort4*)(orow + nb * 16) = o;
            }
        }
    }
}

// ---------------- aggregate + bias + relu + fused BN stats (round-7 form) ----------------
__global__ __launch_bounds__(256) void k_agg(const uint* __restrict__ hm32, const int* __restrict__ esrc,
                                             const int* __restrict__ rs, const float* __restrict__ dinv,
                                             const float* __restrict__ bias, uint* __restrict__ act,
                                             float* __restrict__ bnsum, float* __restrict__ bnsq) {
    __shared__ float ls[128], lq[128];
    int tid = threadIdx.x;
    if (tid < 128) { ls[tid] = 0.f; lq[tid] = 0.f; }
    __syncthreads();
    int lane = tid & 63;
    int wgid = blockIdx.x * 4 + (tid >> 6);
    float2 b2 = *(const float2*)(bias + lane * 2);
    float s0 = 0.f, s1 = 0.f, q0 = 0.f, q1 = 0.f;

    for (int n = wgid; n < NN; n += AGG_WAVES) {
        uint self = hm32[(size_t)n * 64 + lane];
        float a0 = bf_lo(self);
        float a1 = bf_hi(self);

        int i  = __builtin_amdgcn_readfirstlane(rs[n]);
        int i1 = __builtin_amdgcn_readfirstlane(rs[n + 1]);

        int idxv = 0;
        if (i < i1) idxv = esrc[i + min(min(lane, 15), i1 - i - 1)];

        while (i < i1) {
            int cnt = i1 - i;
            cnt = (cnt > 16) ? 16 : cnt;       // wave-uniform
            int cur = idxv;
            int inext = i + cnt;
            if (inext < i1)                    // prefetch next chunk while gathers fly
                idxv = esrc[inext + min(min(lane, 15), i1 - inext - 1)];
            uint g[16];
#pragma unroll
            for (int u = 0; u < 16; ++u) {
                int sidx = __builtin_amdgcn_readlane(cur, u);
                sidx = (u < cnt) ? sidx : NN;  // scalar select -> zero row for pads
                g[u] = hm32[(size_t)sidx * 64 + lane];
            }
#pragma unroll
            for (int u = 0; u < 16; ++u) {
                a0 += bf_lo(g[u]);
                a1 += bf_hi(g[u]);
            }
            i = inext;
        }
        float di = dinv[n];
        float z0 = fmaxf(fmaf(di, a0, b2.x), 0.f);
        float z1 = fmaxf(fmaf(di, a1, b2.y), 0.f);
        act[(size_t)n * 64 + lane] = packbf(z0, z1);
        s0 += z0; s1 += z1;
        q0 += z0 * z0; q1 += z1 * z1;
    }
    atomicAdd(&ls[lane * 2],     s0);
    atomicAdd(&ls[lane * 2 + 1], s1);
    atomicAdd(&lq[lane * 2],     q0);
    atomicAdd(&lq[lane * 2 + 1], q1);
    __syncthreads();
    if (tid < 128) {
        int bkt = blockIdx.x & (NBKT - 1);
        atomicAdd(&bnsum[bkt * 128 + tid], ls[tid]);
        atomicAdd(&bnsq[bkt * 128 + tid],  lq[tid]);
    }
}

// ---------------- per-graph pool + h_cat out-write ----------------
// 64 nodes per block; wave w handles nodes n0 + 2i + w. Lane covers 2 channels.
// out[n][lofs+c] = act*s + t  (coalesced);  gout[g][lofs+c] += s*sum(act) + t*cnt (run-length atomics)
__global__ __launch_bounds__(128) void k_pool(const uint* __restrict__ act32, const float* __restrict__ svec,
                                              const float* __restrict__ tvec, const int* __restrict__ batch,
                                              float* __restrict__ gout, float* __restrict__ outp, int lofs) {
    int t = threadIdx.x;
    int lane = t & 63;
    int w = t >> 6;
    int n0 = blockIdx.x * 64;
    float sc0 = svec[lane * 2], sc1 = svec[lane * 2 + 1];
    float sh0 = tvec[lane * 2], sh1 = tvec[lane * 2 + 1];
    float s0 = 0.f, s1 = 0.f;
    int cnt = 0, curg = -1;
    for (int k = w; k < 64; k += 2) {
        int n = n0 + k;
        if (n >= NN) break;
        int gn = batch[n];
        if (gn != curg) {
            if (cnt) {
                atomicAdd(&gout[(size_t)curg * 384 + lofs + lane * 2],     sc0 * s0 + sh0 * (float)cnt);
                atomicAdd(&gout[(size_t)curg * 384 + lofs + lane * 2 + 1], sc1 * s1 + sh1 * (float)cnt);
            }
            curg = gn; s0 = 0.f; s1 = 0.f; cnt = 0;
        }
        uint v = act32[(size_t)n * 64 + lane];
        float a0 = bf_lo(v), a1 = bf_hi(v);
        float2 z;
        z.x = a0 * sc0 + sh0;
        z.y = a1 * sc1 + sh1;
        *(float2*)(outp + (size_t)n * 384 + lofs + lane * 2) = z;
        s0 += a0;
        s1 += a1;
        ++cnt;
    }
    if (cnt) {
        atomicAdd(&gout[(size_t)curg * 384 + lofs + lane * 2],     sc0 * s0 + sh0 * (float)cnt);
        atomicAdd(&gout[(size_t)curg * 384 + lofs + lane * 2 + 1], sc1 * s1 + sh1 * (float)cnt);
    }
}

extern "C" void kernel_launch(void* const* d_in, const int* in_sizes, int n_in,
                              void* d_out, int out_size, void* d_ws, size_t ws_size,
                              hipStream_t stream) {
    const float* x = (const float*)d_in[0];
    const int* ei = (const int*)d_in[1];
    const int* src = ei;
    const int* dst = ei + NE;
    const int* batch = (const int*)d_in[2];
    const float *W[3], *b[3], *g[3], *beta[3];
    for (int l = 0; l < 3; ++l) {
        W[l]    = (const float*)d_in[3 + 4 * l];
        b[l]    = (const float*)d_in[4 + 4 * l];
        g[l]    = (const float*)d_in[5 + 4 * l];
        beta[l] = (const float*)d_in[6 + 4 * l];
    }
    float* out = (float*)d_out;
    float* gout = out + (size_t)NN * 384;

    char* ws = (char*)d_ws;
    size_t off = 0;
    auto alloc = [&](size_t bytes) -> char* {
        off = (off + 255) & ~(size_t)255;
        char* p = ws + off;
        off += bytes;
        return p;
    };
    ushort* act      = (ushort*)alloc((size_t)NN * 256);        // bf16 relu output (pre-BN)
    ushort* hm       = (ushort*)alloc((size_t)(NN + 1) * 256);  // bf16 hm' rows + zero row at NN
    int*    esrc     = (int*)alloc((size_t)NE * 4);
    int*    tmp      = (int*)alloc((size_t)NE * 4);
    int*    row_start= (int*)alloc((size_t)(NN + 1) * 4);
    float*  dinv     = (float*)alloc((size_t)NN * 4);
    float*  bnst     = (float*)alloc((size_t)3 * 2 * NBKT * 128 * 4);   // [layer][sum|sq][NBKT][128]
    ushort* Wf       = (ushort*)alloc(3 * 16384 * 2);
    ushort* Wff      = (ushort*)alloc(16384 * 2);
    float*  svt      = (float*)alloc(3 * 2 * 128 * 4);                  // [layer][s|t][128]
    float*  tW       = (float*)alloc(128 * 4);
    int*    misc     = (int*)alloc(512 * 4);   // gbh[128], gbase[129], gcur[128]
    int* gbh   = misc;
    int* gbase = misc + 128;
    int* gcur  = misc + 384;
    (void)ws_size;

    hipMemsetAsync(gbh, 0, 128 * 4, stream);
    hipMemsetAsync(hm + (size_t)NN * 128, 0, 256, stream);              // zero row
    hipMemsetAsync(bnst, 0, (size_t)3 * 2 * NBKT * 128 * 4, stream);
    hipMemsetAsync(gout, 0, (size_t)NG * 384 * 4, stream);

    k_bhist<<<512, 256, 0, stream>>>(dst, gbh);
    k_bscan<<<1, 128, 0, stream>>>(gbh, gbase, gcur, row_start);
    k_bin<<<BIN_BLOCKS, 256, 0, stream>>>(src, dst, gcur, tmp);
    k_csr<<<NBUCK, 256, 0, stream>>>(tmp, gbase, esrc, row_start, dinv);
    k_wfrag<<<96, 64, 0, stream>>>(W[0], W[1], W[2], Wf);

    for (int l = 0; l < 3; ++l) {
        float* S = bnst + (size_t)l * 2 * NBKT * 128;
        float* Q = S + NBKT * 128;
        float* sv = svt + l * 256;
        float* tv = sv + 128;
        const ushort* gin = (l == 0) ? (const ushort*)nullptr : act;
        const float* xin = (l == 0) ? x : nullptr;
        const ushort* wfrag = (l == 0) ? (Wf + 0) : Wff;
        const float* tw_in = (l == 0) ? nullptr : tW;

        k_gemm<<<(NN + 63) / 64, 256, 0, stream>>>(gin, xin, wfrag, tw_in, dinv, hm);
        k_agg<<<AGG_BLOCKS, 256, 0, stream>>>((const uint*)hm, esrc, row_start, dinv, b[l],
                                              (uint*)act, S, Q);
        k_finwscale<<<(l < 2) ? 33 : 1, 128, 0, stream>>>(S, Q, g[l], beta[l], sv, tv,
                                                          (l < 2) ? W[l + 1] : nullptr, tW,
                                                          (l < 2) ? (Wf + (l + 1) * 16384) : nullptr, Wff);
        k_pool<<<(NN + 63) / 64, 128, 0, stream>>>((const uint*)act, sv, tv, batch, gout, out, l * 128);
    }
}